// Round 1
// baseline (477.225 us; speedup 1.0000x reference)
//
#include <hip/hip_runtime.h>
#include <hip/hip_bf16.h>

typedef float  f32x4  __attribute__((ext_vector_type(4)));
typedef __bf16 bf16x8 __attribute__((ext_vector_type(8)));
typedef __bf16 bf16x4 __attribute__((ext_vector_type(4)));
typedef __bf16 bf16x2 __attribute__((ext_vector_type(2)));

#define SEQ   4096
#define DDIM  64
#define QB    128
#define KB    64
#define NWAVE 8

// Flash attention forward: one block = 8 waves, each wave owns 16 q-rows.
// K staged [kv][d] bf16 (XOR-swizzled), V staged transposed [d][kv] bf16
// (XOR-swizzled). mfma_f32_16x16x32_bf16 for QK^T and PV; P re-layouted
// through wave-private LDS. Online softmax via 16-lane shfl_xor reduce.
__global__ __launch_bounds__(512)
void fattn_fwd(const float* __restrict__ Qg, const float* __restrict__ Kg,
               const float* __restrict__ Vg, float* __restrict__ Og)
{
    __shared__ __align__(16) char smem[8192 * 2 + NWAVE * 2048];
    char* KsB = smem;            // [64][64] bf16, swizzled
    char* VtB = smem + 8192;     // [64][64] bf16, transposed, swizzled
    char* PbB = smem + 16384;    // [NWAVE][16][64] bf16, swizzled

    const int tid  = threadIdx.x;
    const int w    = tid >> 6;
    const int lane = tid & 63;
    const int g    = lane >> 4;
    const int lr   = lane & 15;

    const int bh = blockIdx.x >> 5;          // 32 q-blocks per (b,h)
    const int qb = blockIdx.x & 31;
    const size_t base = (size_t)bh * SEQ * DDIM;
    const int qrow0 = qb * QB + w * 16;

    // Q fragments (A operand), pre-scaled by 1/sqrt(D) = 0.125 (exact pow2)
    bf16x8 aq[2];
    {
        const float* qp = Qg + base + (size_t)(qrow0 + lr) * DDIM + 8 * g;
        #pragma unroll
        for (int c = 0; c < 2; ++c) {
            float4 f0 = *(const float4*)(qp + 32 * c);
            float4 f1 = *(const float4*)(qp + 32 * c + 4);
            aq[c][0] = (__bf16)(f0.x * 0.125f);
            aq[c][1] = (__bf16)(f0.y * 0.125f);
            aq[c][2] = (__bf16)(f0.z * 0.125f);
            aq[c][3] = (__bf16)(f0.w * 0.125f);
            aq[c][4] = (__bf16)(f1.x * 0.125f);
            aq[c][5] = (__bf16)(f1.y * 0.125f);
            aq[c][6] = (__bf16)(f1.z * 0.125f);
            aq[c][7] = (__bf16)(f1.w * 0.125f);
        }
    }

    f32x4 o[4];
    #pragma unroll
    for (int n = 0; n < 4; ++n) o[n] = (f32x4){0.f, 0.f, 0.f, 0.f};
    float mrow[4], lrow[4];
    #pragma unroll
    for (int r = 0; r < 4; ++r) { mrow[r] = -1e30f; lrow[r] = 0.f; }

    char* Pw = PbB + w * 2048;

    for (int kt = 0; kt < SEQ / KB; ++kt) {
        const float* kp = Kg + base + (size_t)(kt * KB) * DDIM;
        const float* vp = Vg + base + (size_t)(kt * KB) * DDIM;
        __syncthreads();   // previous tile's LDS reads done before overwrite

        // stage K: bf16 rows [kv][64], swizzle byte ^= (kv&7)<<4
        #pragma unroll
        for (int j = 0; j < 2; ++j) {
            int i  = tid + 512 * j;
            int kv = i >> 4;
            int d  = (i & 15) * 4;
            float4 f = *(const float4*)(kp + kv * 64 + d);
            bf16x4 pk;
            pk[0] = (__bf16)f.x; pk[1] = (__bf16)f.y;
            pk[2] = (__bf16)f.z; pk[3] = (__bf16)f.w;
            int off = (kv * 128 + d * 2) ^ ((kv & 7) << 4);
            *(bf16x4*)(KsB + off) = pk;
        }
        // stage V transposed: Vt[d][kv], pair of kv per 4B write
        {
            int kv0 = (tid >> 4) * 2;
            int d0  = (tid & 15) * 4;
            float4 f0 = *(const float4*)(vp + kv0 * 64 + d0);
            float4 f1 = *(const float4*)(vp + (kv0 + 1) * 64 + d0);
            float a0[4] = {f0.x, f0.y, f0.z, f0.w};
            float a1[4] = {f1.x, f1.y, f1.z, f1.w};
            #pragma unroll
            for (int q = 0; q < 4; ++q) {
                int row = d0 + q;
                int off = (row * 128 + kv0 * 2) ^ ((row & 7) << 4);
                bf16x2 pv2;
                pv2[0] = (__bf16)a0[q];
                pv2[1] = (__bf16)a1[q];
                *(bf16x2*)(VtB + off) = pv2;
            }
        }
        __syncthreads();

        // S = (Q*scale) K^T : 2 d-chunks x 4 kv-subtiles
        f32x4 s[4];
        #pragma unroll
        for (int n = 0; n < 4; ++n) s[n] = (f32x4){0.f, 0.f, 0.f, 0.f};
        #pragma unroll
        for (int c = 0; c < 2; ++c) {
            #pragma unroll
            for (int n = 0; n < 4; ++n) {
                int kvr = n * 16 + lr;
                int off = (kvr * 128 + c * 64 + g * 16) ^ ((kvr & 7) << 4);
                bf16x8 bk = *(const bf16x8*)(KsB + off);
                s[n] = __builtin_amdgcn_mfma_f32_16x16x32_bf16(aq[c], bk, s[n], 0, 0, 0);
            }
        }

        // online softmax (rows live in 16-lane groups) + P -> LDS (bf16)
        #pragma unroll
        for (int r = 0; r < 4; ++r) {
            float tm = fmaxf(fmaxf(s[0][r], s[1][r]), fmaxf(s[2][r], s[3][r]));
            #pragma unroll
            for (int mk = 1; mk < 16; mk <<= 1)
                tm = fmaxf(tm, __shfl_xor(tm, mk, 64));
            float mn   = fmaxf(mrow[r], tm);
            float corr = __expf(mrow[r] - mn);
            float pv[4];
            #pragma unroll
            for (int n = 0; n < 4; ++n) pv[n] = __expf(s[n][r] - mn);
            float ps = (pv[0] + pv[1]) + (pv[2] + pv[3]);
            #pragma unroll
            for (int mk = 1; mk < 16; mk <<= 1)
                ps += __shfl_xor(ps, mk, 64);
            lrow[r] = lrow[r] * corr + ps;
            mrow[r] = mn;
            #pragma unroll
            for (int n = 0; n < 4; ++n) o[n][r] *= corr;
            int rr = g * 4 + r;
            #pragma unroll
            for (int n = 0; n < 4; ++n) {
                int off = (rr * 128 + (n * 16 + lr) * 2) ^ ((rr & 7) << 4);
                *(__bf16*)(Pw + off) = (__bf16)pv[n];
            }
        }

        // O += P V : 2 kv-chunks x 4 d-subtiles
        #pragma unroll
        for (int c = 0; c < 2; ++c) {
            int offp = (lr * 128 + c * 64 + g * 16) ^ ((lr & 7) << 4);
            bf16x8 ap = *(const bf16x8*)(Pw + offp);
            #pragma unroll
            for (int n = 0; n < 4; ++n) {
                int dr   = n * 16 + lr;
                int offv = (dr * 128 + c * 64 + g * 16) ^ ((dr & 7) << 4);
                bf16x8 bv = *(const bf16x8*)(VtB + offv);
                o[n] = __builtin_amdgcn_mfma_f32_16x16x32_bf16(ap, bv, o[n], 0, 0, 0);
            }
        }
    }

    // epilogue: O / l
    float* op = Og + base;
    #pragma unroll
    for (int r = 0; r < 4; ++r) {
        float inv = 1.0f / lrow[r];
        int row = qrow0 + g * 4 + r;
        #pragma unroll
        for (int n = 0; n < 4; ++n)
            op[(size_t)row * 64 + n * 16 + lr] = o[n][r] * inv;
    }
}

extern "C" void kernel_launch(void* const* d_in, const int* in_sizes, int n_in,
                              void* d_out, int out_size, void* d_ws, size_t ws_size,
                              hipStream_t stream) {
    const float* Q = (const float*)d_in[0];
    const float* K = (const float*)d_in[1];
    const float* V = (const float*)d_in[2];
    float* O = (float*)d_out;
    dim3 grid(32 * (SEQ / QB));   // 32 (b,h) * 32 q-blocks = 1024
    dim3 block(512);
    fattn_fwd<<<grid, block, 0, stream>>>(Q, K, V, O);
}

// Round 2
// 179.285 us; speedup vs baseline: 2.6618x; 2.6618x over previous
//
#include <hip/hip_runtime.h>
#include <hip/hip_bf16.h>

typedef float  f32x16 __attribute__((ext_vector_type(16)));
typedef __bf16 bf16x8 __attribute__((ext_vector_type(8)));
typedef __bf16 bf16x4 __attribute__((ext_vector_type(4)));
typedef __bf16 bf16x2 __attribute__((ext_vector_type(2)));
typedef int    i32x2v __attribute__((ext_vector_type(2)));
typedef int    i32x4v __attribute__((ext_vector_type(4)));

#define SEQ   4096
#define DDIM  64
#define QB    256
#define KB    64
#define NT    (SEQ / KB)
#define SCL   0.18033688011112042f   // 0.125 * log2(e) -> softmax in exp2 domain
#define DEFT  16.0f                  // defer-max threshold (log2 units)

#if __has_builtin(__builtin_amdgcn_exp2f)
#define EXP2(x) __builtin_amdgcn_exp2f(x)
#else
#define EXP2(x) __expf((x) * 0.6931471805599453f)
#endif

// LDS swizzle: XOR row bits into the 16B-slot index (bank-minimum for b128
// fragment reads AND for the b64/b32 staging writes).
__device__ __forceinline__ int swzrow(int row) {
  return (((row & 7) ^ ((row >> 3) & 3)) << 4);
}

__device__ __forceinline__ void pswap32(int &x, int &y) {
#if __has_builtin(__builtin_amdgcn_permlane32_swap)
  i32x2v r = __builtin_amdgcn_permlane32_swap(x, y, false, false);
  x = r[0]; y = r[1];
#else
  asm volatile("v_permlane32_swap_b32 %0, %1" : "+v"(x), "+v"(y));
#endif
}

__device__ __forceinline__ bf16x4 cvt4(float4 f) {
  bf16x4 r;
  r[0] = (__bf16)f.x; r[1] = (__bf16)f.y; r[2] = (__bf16)f.z; r[3] = (__bf16)f.w;
  return r;
}

__device__ __forceinline__ bf16x8 mkfrag(int a, int b, int c, int d) {
  i32x4v v; v[0] = a; v[1] = b; v[2] = c; v[3] = d;
  return __builtin_bit_cast(bf16x8, v);
}

// Flash attention fwd, 8 waves x 32 q-rows (QB=256), KB=64, 32x32x16 MFMA.
// Swapped QK^T: S^T = mfma(K, Q) -> each lane owns one q-row (32 kv vals).
// P redistributed to the PV B-fragment fully in-register (permlane32_swap).
// K/V double-buffered in LDS (bf16, XOR-swizzled), async-stage split.
__global__ __launch_bounds__(512, 4)
void fattn(const float* __restrict__ Qg, const float* __restrict__ Kg,
           const float* __restrict__ Vg, float* __restrict__ Og)
{
  __shared__ __align__(16) char smem[32768];  // 2 x (K 8KB + Vt 8KB)

  const int tid  = threadIdx.x;
  const int w    = tid >> 6;
  const int lane = tid & 63;
  const int q31  = lane & 31;
  const int h    = lane >> 5;

  int wg = (int)blockIdx.x;
  wg = (wg & 7) * 64 + (wg >> 3);      // XCD-chunked swizzle (512 = 8*64)
  const int bh = wg >> 4;
  const int qb = wg & 15;
  const size_t base = (size_t)bh * (SEQ * DDIM);
  const int qrow = qb * QB + w * 32 + q31;

  // ---- Q B-fragments (pre-scaled): aq[c][j] = Q[qrow][16c + 8h + j] * SCL
  bf16x8 aq[4];
  {
    const float* qp = Qg + base + (size_t)qrow * DDIM + 8 * h;
    #pragma unroll
    for (int c = 0; c < 4; ++c) {
      float4 f0 = *(const float4*)(qp + 16 * c);
      float4 f1 = *(const float4*)(qp + 16 * c + 4);
      aq[c][0] = (__bf16)(f0.x * SCL);
      aq[c][1] = (__bf16)(f0.y * SCL);
      aq[c][2] = (__bf16)(f0.z * SCL);
      aq[c][3] = (__bf16)(f0.w * SCL);
      aq[c][4] = (__bf16)(f1.x * SCL);
      aq[c][5] = (__bf16)(f1.y * SCL);
      aq[c][6] = (__bf16)(f1.z * SCL);
      aq[c][7] = (__bf16)(f1.w * SCL);
    }
  }

  // ---- staging assignments
  const int kvA = tid >> 4;                 // K rows 0..31 (chunk B = +32)
  const int dK  = (tid & 15) * 4;
  const int kw0 = ((kvA * 128 + dK * 2) ^ swzrow(kvA)); // swz same for +32
  const int kv0 = (tid >> 4) * 2;           // V row pair
  const int dV  = (tid & 15) * 4;
  int vw[4];
  #pragma unroll
  for (int qq = 0; qq < 4; ++qq)
    vw[qq] = 8192 + (((dV + qq) * 128 + kv0 * 2) ^ swzrow(dV + qq));

  const float* kptr = Kg + base + (size_t)kvA * DDIM + dK;
  const float* vptr = Vg + base + (size_t)kv0 * DDIM + dV;

  // ---- fragment read addresses: row = 32*sub + q31, byte = (32c+16h)^swz
  const int swr = swzrow(q31);
  int kaddr[4];
  #pragma unroll
  for (int c = 0; c < 4; ++c)
    kaddr[c] = q31 * 128 + ((32 * c + 16 * h) ^ swr);

  f32x16 o0 = {}, o1 = {};
  float mrow = 0.f, lsum = 0.f;

  // ---- prologue: stage tile 0 -> buf0
  {
    float4 ka = *(const float4*)(kptr);
    float4 kb = *(const float4*)(kptr + 32 * DDIM);
    float4 va = *(const float4*)(vptr);
    float4 vb = *(const float4*)(vptr + DDIM);
    *(bf16x4*)(smem + kw0)            = cvt4(ka);
    *(bf16x4*)(smem + kw0 + 32 * 128) = cvt4(kb);
    float va4[4] = {va.x, va.y, va.z, va.w};
    float vb4[4] = {vb.x, vb.y, vb.z, vb.w};
    #pragma unroll
    for (int qq = 0; qq < 4; ++qq) {
      bf16x2 p; p[0] = (__bf16)va4[qq]; p[1] = (__bf16)vb4[qq];
      *(bf16x2*)(smem + vw[qq]) = p;
    }
  }

  int rbase = 0;

  for (int t = 0; t < NT; ++t) {
    __syncthreads();
    const bool more = (t + 1) < NT;
    const float* kpt = kptr + (size_t)(t + 1) * (KB * DDIM);
    const float* vpt = vptr + (size_t)(t + 1) * (KB * DDIM);

    // issue K(t+1) loads early (hidden under QK + softmax)
    float4 ka = {}, kb = {};
    if (more) {
      ka = *(const float4*)(kpt);
      kb = *(const float4*)(kpt + 32 * DDIM);
    }

    // ---- QK^T (swapped): S^T[kv][q] ; A = K rows, B = Q
    f32x16 s0 = {}, s1 = {};
    #pragma unroll
    for (int c = 0; c < 4; ++c) {
      bf16x8 k0 = *(const bf16x8*)(smem + rbase + kaddr[c]);
      bf16x8 k1 = *(const bf16x8*)(smem + rbase + kaddr[c] + 4096);
      s0 = __builtin_amdgcn_mfma_f32_32x32x16_bf16(k0, aq[c], s0, 0, 0, 0);
      s1 = __builtin_amdgcn_mfma_f32_32x32x16_bf16(k1, aq[c], s1, 0, 0, 0);
    }

    // issue V(t+1) loads (hidden under softmax + PV)
    float4 va = {}, vb = {};
    if (more) {
      va = *(const float4*)(vpt);
      vb = *(const float4*)(vpt + DDIM);
    }

    // ---- softmax: defer-max (log2 domain), per-lane row, no per-tile shuffles
    float pm;
    {
      float a = fmaxf(fmaxf(fmaxf(s0[0], s0[1]), fmaxf(s0[2], s0[3])),
                      fmaxf(fmaxf(s0[4], s0[5]), fmaxf(s0[6], s0[7])));
      float b = fmaxf(fmaxf(fmaxf(s0[8], s0[9]), fmaxf(s0[10], s0[11])),
                      fmaxf(fmaxf(s0[12], s0[13]), fmaxf(s0[14], s0[15])));
      float c = fmaxf(fmaxf(fmaxf(s1[0], s1[1]), fmaxf(s1[2], s1[3])),
                      fmaxf(fmaxf(s1[4], s1[5]), fmaxf(s1[6], s1[7])));
      float d = fmaxf(fmaxf(fmaxf(s1[8], s1[9]), fmaxf(s1[10], s1[11])),
                      fmaxf(fmaxf(s1[12], s1[13]), fmaxf(s1[14], s1[15])));
      pm = fmaxf(fmaxf(a, b), fmaxf(c, d));
    }
    if (!__all(pm <= mrow + DEFT)) {      // rare/never on this data
      float tm = fmaxf(pm, __shfl_xor(pm, 32));
      float mn = fmaxf(mrow, tm);
      float corr = EXP2(mrow - mn);
      o0 *= corr; o1 *= corr;
      lsum *= corr;
      mrow = mn;
    }
    #pragma unroll
    for (int r = 0; r < 16; ++r) s0[r] = EXP2(s0[r] - mrow);
    #pragma unroll
    for (int r = 0; r < 16; ++r) s1[r] = EXP2(s1[r] - mrow);

    f32x16 ts = s0 + s1;
    lsum += ((((ts[0]+ts[1])+(ts[2]+ts[3])) + ((ts[4]+ts[5])+(ts[6]+ts[7])))
          +  (((ts[8]+ts[9])+(ts[10]+ts[11])) + ((ts[12]+ts[13])+(ts[14]+ts[15]))));

    // ---- pack P to bf16 pairs, then in-register transpose to B-fragments
    int pk[2][8];
    #pragma unroll
    for (int u = 0; u < 8; ++u) {
      bf16x2 p0; p0[0] = (__bf16)s0[2*u]; p0[1] = (__bf16)s0[2*u+1];
      pk[0][u] = __builtin_bit_cast(int, p0);
      bf16x2 p1; p1[0] = (__bf16)s1[2*u]; p1[1] = (__bf16)s1[2*u+1];
      pk[1][u] = __builtin_bit_cast(int, p1);
    }
    #pragma unroll
    for (int m = 0; m < 2; ++m) {
      pswap32(pk[m][0], pk[m][2]);
      pswap32(pk[m][1], pk[m][3]);
      pswap32(pk[m][4], pk[m][6]);
      pswap32(pk[m][5], pk[m][7]);
    }

    // ---- write K(t+1) to the other buffer
    const int wb = rbase ^ 16384;
    if (more) {
      *(bf16x4*)(smem + wb + kw0)            = cvt4(ka);
      *(bf16x4*)(smem + wb + kw0 + 32 * 128) = cvt4(kb);
    }

    // ---- PV: O^T += Vt * P   (A = Vt rows d, B = P fragment)
    #pragma unroll
    for (int c = 0; c < 4; ++c) {
      bf16x8 bp = mkfrag(pk[c>>1][(c&1)*4+0], pk[c>>1][(c&1)*4+1],
                         pk[c>>1][(c&1)*4+2], pk[c>>1][(c&1)*4+3]);
      bf16x8 v0 = *(const bf16x8*)(smem + rbase + kaddr[c] + 8192);
      bf16x8 v1 = *(const bf16x8*)(smem + rbase + kaddr[c] + 12288);
      o0 = __builtin_amdgcn_mfma_f32_32x32x16_bf16(v0, bp, o0, 0, 0, 0);
      o1 = __builtin_amdgcn_mfma_f32_32x32x16_bf16(v1, bp, o1, 0, 0, 0);
    }

    // ---- write V(t+1) (transposed) to the other buffer
    if (more) {
      float va4[4] = {va.x, va.y, va.z, va.w};
      float vb4[4] = {vb.x, vb.y, vb.z, vb.w};
      #pragma unroll
      for (int qq = 0; qq < 4; ++qq) {
        bf16x2 p; p[0] = (__bf16)va4[qq]; p[1] = (__bf16)vb4[qq];
        *(bf16x2*)(smem + wb + vw[qq]) = p;
      }
    }
    rbase ^= 16384;
  }

  // ---- epilogue: O[q][d] = o / l ; d = 32*sub + 8*rg + 4h + i
  float l = lsum + __shfl_xor(lsum, 32);
  float inv = 1.0f / l;
  float* op = Og + base + (size_t)qrow * DDIM + 4 * h;
  #pragma unroll
  for (int rg = 0; rg < 4; ++rg) {
    float4 st0 = { o0[4*rg+0]*inv, o0[4*rg+1]*inv, o0[4*rg+2]*inv, o0[4*rg+3]*inv };
    *(float4*)(op + 8*rg) = st0;
    float4 st1 = { o1[4*rg+0]*inv, o1[4*rg+1]*inv, o1[4*rg+2]*inv, o1[4*rg+3]*inv };
    *(float4*)(op + 8*rg + 32) = st1;
  }
}

extern "C" void kernel_launch(void* const* d_in, const int* in_sizes, int n_in,
                              void* d_out, int out_size, void* d_ws, size_t ws_size,
                              hipStream_t stream) {
  const float* Q = (const float*)d_in[0];
  const float* K = (const float*)d_in[1];
  const float* V = (const float*)d_in[2];
  float* O = (float*)d_out;
  dim3 grid(32 * (SEQ / QB));   // 32 (b,h) * 16 q-blocks = 512
  dim3 block(512);
  fattn<<<grid, block, 0, stream>>>(Q, K, V, O);
}